// Round 9
// baseline (199.383 us; speedup 1.0000x reference)
//
#include <hip/hip_runtime.h>
#include <hip/hip_cooperative_groups.h>

// MixtureRouting: y[b,d,m] = sum_p x[b,d,p] * coef[b,p,m]
//   lh[b,p,m]  = pi[b,m] * prod_i( sig[b,i,m] / (PI*((mu[b,i,p]-mu[b,i,m])^2 + sig[b,i,m]^2)) )
//   coef[p,m]  = lh[p,m] / rowsum[p]
// R8 -> R9: R8's cooperative launch silently failed (output untouched): 512x512-thread
// blocks with 48 KB LDS + unbounded VGPR couldn't co-reside 2/CU. Occupancy-proof
// config: 512 blocks x 256 threads, 32 KB LDS, __launch_bounds__(256,2) -> 2 blocks/CU
// feasible for ANY allocator outcome (VGPR<=256, LDS 64<=160 KB). Phases (R7-verified
// math): A rowsum partials, B xbf=bf16(x*invrow), C fused-lh bf16-MFMA gemm.
// Fallback: if the coop launch is rejected, run the verified R7 3-kernel path.

namespace cg = cooperative_groups;

typedef float v4f __attribute__((ext_vector_type(4)));
typedef float f32x4 __attribute__((ext_vector_type(4)));
typedef short bf16x8 __attribute__((ext_vector_type(8)));

namespace {
constexpr int BB = 4;
constexpr int DD = 81;
constexpr int KK = 2048;
constexpr int MROWS = 96;                 // padded d-rows for MFMA (6 tiles of 16)
constexpr int NBLK = 512;
constexpr int NTHR = 256;
constexpr float INV_PI4 = 1.0f / 97.40909103400243f;

// ws layout (bytes); rowsumPart sized for 8 slices (fallback uses 8, coop uses 4)
constexpr size_t OFF_XBF = 0;                                     // ushort[B][96][K]
constexpr size_t OFF_RSP = (size_t)BB * MROWS * KK * 2;           // float[B][8][K]
}

__device__ __forceinline__ unsigned short f2bf(float f) {
    union { float f; unsigned int u; } v; v.f = f;
    unsigned int u = v.u;
    unsigned int r = (u + 0x7FFFu + ((u >> 16) & 1u)) >> 16;   // RNE
    return (unsigned short)r;
}

// ===========================================================================
// Cooperative fused kernel: 512 blocks x 256 threads (4 waves), 32 KB LDS.
// ===========================================================================
__global__ __launch_bounds__(NTHR, 2) void fused_kernel(const float* __restrict__ x,
                                                        const float* __restrict__ pi_,
                                                        const float* __restrict__ mu,
                                                        const float* __restrict__ sig,
                                                        unsigned short* __restrict__ xbf,
                                                        float* __restrict__ rowsumPart,
                                                        float* __restrict__ out) {
    __shared__ __align__(16) char smem[32768];
    cg::grid_group grid = cg::this_grid();

    int g = blockIdx.x;
    int t = threadIdx.x;
    int lane = t & 63, w = t >> 6;                      // 4 waves

    // ---------------- Phase A: rowsum partials ----------------
    // block = (b, pc 64-p chunk, ms 512-m slice); grid = 4*32*4 = 512.
    // wave w sums its 128-m quarter; rowsumPart[b][ms][p0+lane] = slice sum.
    {
        v4f*   mush = (v4f*)smem;                       // [512]  8 KB
        v4f*   s2sh = (v4f*)(smem + 8192);              // [512]  8 KB
        float* csh  = (float*)(smem + 16384);           // [512]  2 KB
        float* red  = (float*)(smem + 18432);           // [4][64] 1 KB

        int b  = g >> 7;
        int pc = (g & 127) >> 2;                        // 0..31
        int ms = g & 3;                                 // 0..3
        int p0 = pc * 64;
        int m0 = ms * 512;

        const float* mub = mu  + (size_t)b * 4 * KK;
        const float* sgb = sig + (size_t)b * 4 * KK;
        const float* pib = pi_ + (size_t)b * KK;

        for (int i = t; i < 512; i += NTHR) {
            int m = m0 + i;
            v4f mm = {mub[m], mub[KK + m], mub[2 * KK + m], mub[3 * KK + m]};
            v4f sg = {sgb[m], sgb[KK + m], sgb[2 * KK + m], sgb[3 * KK + m]};
            mush[i] = mm;
            s2sh[i] = sg * sg;
            csh[i]  = pib[m] * ((sg.x * sg.y) * (sg.z * sg.w)) * INV_PI4;
        }
        int p = p0 + lane;
        v4f mp = {mub[p], mub[KK + p], mub[2 * KK + p], mub[3 * KK + p]};
        __syncthreads();

        float sum = 0.f;
#pragma unroll 4
        for (int i = 0; i < 128; ++i) {
            int mi = w * 128 + i;                       // this wave's 128 m's
            v4f d = mp - mush[mi];
            v4f q = d * d + s2sh[mi];
            float den = (q.x * q.y) * (q.z * q.w);
            sum += csh[mi] * __builtin_amdgcn_rcpf(den);
        }

        red[w * 64 + lane] = sum;
        __syncthreads();
        if (t < 64)
            rowsumPart[((size_t)(b * 4 + ms)) * KK + p0 + t] =
                red[t] + red[64 + t] + red[128 + t] + red[192 + t];
    }

    grid.sync();

    // ---------------- Phase B: xbf = bf16(x * invrow), 96 rows (81..95 zero) --------
    {
        const size_t NE = (size_t)BB * MROWS * KK;      // 786432 -> 6 per thread
        size_t tid = (size_t)g * NTHR + t;
        for (size_t e = tid; e < NE; e += (size_t)NBLK * NTHR) {
            int p  = (int)(e & (KK - 1));
            int bd = (int)(e >> 11);                    // b*96 + d
            int b  = bd / MROWS;
            int d  = bd - b * MROWS;
            const float* rsp = rowsumPart + (size_t)b * 4 * KK + p;
            float rs = rsp[0] + rsp[KK] + rsp[2 * KK] + rsp[3 * KK];
            float v = 0.f;
            if (d < DD) v = x[((size_t)(b * DD + d)) * KK + p] * __builtin_amdgcn_rcpf(rs);
            xbf[e] = f2bf(v);
        }
    }

    grid.sync();

    // ---------------- Phase C: fused-lh MFMA gemm ----------------
    // block = (b, 16-col m-tile); wave w owns p-slice [w*512, w*512+512) = 16 ks-steps.
    {
        v4f* mus = (v4f*)smem;                          // [2048] 32 KB during K-loop
        f32x4 (*red)[6][64] = (f32x4 (*)[6][64])smem;   // [4][6][64] 24 KB after barrier

        int r = lane & 15, q = lane >> 4;
        int b  = g >> 7;
        int m0 = (g & 127) * 16;

        const float* mub = mu  + (size_t)b * 4 * KK;
        const float* sgb = sig + (size_t)b * 4 * KK;

        __syncthreads();                                // phase A red[] still in smem
        for (int i = t; i < KK; i += NTHR)
            mus[i] = (v4f){mub[i], mub[KK + i], mub[2 * KK + i], mub[3 * KK + i]};

        int m = m0 + r;
        v4f mm = {mub[m], mub[KK + m], mub[2 * KK + m], mub[3 * KK + m]};
        v4f sg = {sgb[m], sgb[KK + m], sgb[2 * KK + m], sgb[3 * KK + m]};
        v4f s2 = sg * sg;
        float cm = pi_[(size_t)b * KK + m] * ((sg.x * sg.y) * (sg.z * sg.w)) * INV_PI4;

        const unsigned short* Abase = xbf + ((size_t)(b * MROWS + r)) * KK;

        f32x4 acc[6];
#pragma unroll
        for (int i = 0; i < 6; ++i) acc[i] = (f32x4)0.f;

        __syncthreads();

        int pw = w * 512;
#pragma unroll 4
        for (int ks = 0; ks < 16; ++ks) {
            int pb = pw + ks * 32 + q * 8;
            bf16x8 Bf;
#pragma unroll
            for (int j = 0; j < 8; ++j) {
                v4f mp = mus[pb + j];
                v4f dd = mp - mm;
                v4f qq = dd * dd + s2;
                float den = (qq.x * qq.y) * (qq.z * qq.w);
                float lh = cm * __builtin_amdgcn_rcpf(den);
                Bf[j] = (short)f2bf(lh);
            }
            bf16x8 Af[6];
#pragma unroll
            for (int Mt = 0; Mt < 6; ++Mt)
                Af[Mt] = *(const bf16x8*)(Abase + (size_t)Mt * 16 * KK + pb);
#pragma unroll
            for (int Mt = 0; Mt < 6; ++Mt)
                acc[Mt] = __builtin_amdgcn_mfma_f32_16x16x32_bf16(Af[Mt], Bf, acc[Mt], 0, 0, 0);
        }

        __syncthreads();                                // done reading mus
#pragma unroll
        for (int Mt = 0; Mt < 6; ++Mt)
            red[w][Mt][lane] = acc[Mt];
        __syncthreads();

        // 1536 outputs (96 rows x 16 cols) -> 6 per thread; skip d >= 81.
        int col = t & 15;
        int dr  = t >> 4;                               // 0..15
#pragma unroll
        for (int k = 0; k < 6; ++k) {
            int d = dr + 16 * k;                        // 0..95
            if (d < DD) {
                int Mt  = d >> 4;
                int row = d & 15;
                int l   = (row >> 2) * 16 + col;
                int j   = row & 3;
                float s = red[0][Mt][l][j] + red[1][Mt][l][j] +
                          red[2][Mt][l][j] + red[3][Mt][l][j];
                out[((size_t)(b * DD + d)) * KK + m0 + col] = s;
            }
        }
    }
}

// ===========================================================================
// Fallback path: the verified R7 three-kernel pipeline.
// ===========================================================================
__global__ __launch_bounds__(256) void rowsum_kernel(const float* __restrict__ pi_,
                                                     const float* __restrict__ mu,
                                                     const float* __restrict__ sig,
                                                     float* __restrict__ rowsumPart) {
    __shared__ v4f   mush[256];
    __shared__ v4f   s2sh[256];
    __shared__ float csh[256];
    __shared__ float red[4][64];

    int blk = blockIdx.x;
    int b   = blk >> 8;
    int pc  = (blk & 255) >> 3;
    int ms  = blk & 7;
    int p0  = pc * 64;
    int m0  = ms * 256;
    int t   = threadIdx.x;
    int lane = t & 63, w = t >> 6;

    const float* mub = mu  + (size_t)b * 4 * KK;
    const float* sgb = sig + (size_t)b * 4 * KK;
    const float* pib = pi_ + (size_t)b * KK;

    {
        int m = m0 + t;
        v4f mm = {mub[m], mub[KK + m], mub[2 * KK + m], mub[3 * KK + m]};
        v4f sg = {sgb[m], sgb[KK + m], sgb[2 * KK + m], sgb[3 * KK + m]};
        mush[t] = mm;
        s2sh[t] = sg * sg;
        csh[t]  = pib[m] * ((sg.x * sg.y) * (sg.z * sg.w)) * INV_PI4;
    }
    int p = p0 + lane;
    v4f mp = {mub[p], mub[KK + p], mub[2 * KK + p], mub[3 * KK + p]};
    __syncthreads();

    float sum = 0.f;
#pragma unroll 4
    for (int i = 0; i < 64; ++i) {
        int mi = w * 64 + i;
        v4f d = mp - mush[mi];
        v4f q = d * d + s2sh[mi];
        float den = (q.x * q.y) * (q.z * q.w);
        sum += csh[mi] * __builtin_amdgcn_rcpf(den);
    }

    red[w][lane] = sum;
    __syncthreads();
    if (t < 64)
        rowsumPart[((size_t)(b * 8 + ms)) * KK + p0 + t] =
            red[0][t] + red[1][t] + red[2][t] + red[3][t];
}

__global__ __launch_bounds__(256) void xbf_kernel(const float* __restrict__ x,
                                                  const float* __restrict__ rowsumPart,
                                                  unsigned short* __restrict__ xbf) {
    int d = blockIdx.x;
    int b = blockIdx.y;
    int t = threadIdx.x;
    unsigned short* orow = xbf + ((size_t)(b * MROWS + d)) * KK;
    const float* xrow = x + ((size_t)(b * DD + d)) * KK;
    const float* rsp  = rowsumPart + (size_t)b * 8 * KK;
#pragma unroll
    for (int j = 0; j < 8; ++j) {
        int p = j * 256 + t;
        float rs = 0.f;
#pragma unroll
        for (int s = 0; s < 8; ++s) rs += rsp[(size_t)s * KK + p];
        float v = 0.f;
        if (d < DD) v = xrow[p] * __builtin_amdgcn_rcpf(rs);
        orow[p] = f2bf(v);
    }
}

__global__ __launch_bounds__(512) void gemm_kernel(const float* __restrict__ pi_,
                                                   const float* __restrict__ mu,
                                                   const float* __restrict__ sig,
                                                   const unsigned short* __restrict__ xbf,
                                                   float* __restrict__ out) {
    __shared__ __align__(16) char smem2[49152];
    v4f* mus = (v4f*)smem2;
    f32x4 (*red)[6][64] = (f32x4 (*)[6][64])smem2;

    int t = threadIdx.x;
    int w = t >> 6, lane = t & 63;
    int r = lane & 15, q = lane >> 4;
    int b  = blockIdx.y;
    int m0 = blockIdx.x * 16;

    const float* mub = mu  + (size_t)b * 4 * KK;
    const float* sgb = sig + (size_t)b * 4 * KK;

    for (int i = t; i < KK; i += 512)
        mus[i] = (v4f){mub[i], mub[KK + i], mub[2 * KK + i], mub[3 * KK + i]};

    int m = m0 + r;
    v4f mm = {mub[m], mub[KK + m], mub[2 * KK + m], mub[3 * KK + m]};
    v4f sg = {sgb[m], sgb[KK + m], sgb[2 * KK + m], sgb[3 * KK + m]};
    v4f s2 = sg * sg;
    float cm = pi_[(size_t)b * KK + m] * ((sg.x * sg.y) * (sg.z * sg.w)) * INV_PI4;

    const unsigned short* Abase = xbf + ((size_t)(b * MROWS + r)) * KK;

    f32x4 acc[6];
#pragma unroll
    for (int i = 0; i < 6; ++i) acc[i] = (f32x4)0.f;

    __syncthreads();

    int pw = w * 256;
#pragma unroll
    for (int ks = 0; ks < 8; ++ks) {
        int pb = pw + ks * 32 + q * 8;
        bf16x8 Bf;
#pragma unroll
        for (int j = 0; j < 8; ++j) {
            v4f mp = mus[pb + j];
            v4f dd = mp - mm;
            v4f qq = dd * dd + s2;
            float den = (qq.x * qq.y) * (qq.z * qq.w);
            float lh = cm * __builtin_amdgcn_rcpf(den);
            Bf[j] = (short)f2bf(lh);
        }
        bf16x8 Af[6];
#pragma unroll
        for (int Mt = 0; Mt < 6; ++Mt)
            Af[Mt] = *(const bf16x8*)(Abase + (size_t)Mt * 16 * KK + pb);
#pragma unroll
        for (int Mt = 0; Mt < 6; ++Mt)
            acc[Mt] = __builtin_amdgcn_mfma_f32_16x16x32_bf16(Af[Mt], Bf, acc[Mt], 0, 0, 0);
    }

    __syncthreads();
#pragma unroll
    for (int Mt = 0; Mt < 6; ++Mt)
        red[w][Mt][lane] = acc[Mt];
    __syncthreads();

    int col = t & 15;
    int dr  = t >> 4;
#pragma unroll
    for (int k = 0; k < 3; ++k) {
        int d = dr + 32 * k;
        if (d < DD) {
            int Mt  = d >> 4;
            int row = d & 15;
            int l   = (row >> 2) * 16 + col;
            int j   = row & 3;
            float s = 0.f;
#pragma unroll
            for (int ww = 0; ww < 8; ++ww) s += red[ww][Mt][l][j];
            out[((size_t)(b * DD + d)) * KK + m0 + col] = s;
        }
    }
}

extern "C" void kernel_launch(void* const* d_in, const int* in_sizes, int n_in,
                              void* d_out, int out_size, void* d_ws, size_t ws_size,
                              hipStream_t stream) {
    const float* x   = (const float*)d_in[0];
    const float* pi_ = (const float*)d_in[1];
    const float* mu  = (const float*)d_in[2];
    const float* sig = (const float*)d_in[3];
    float* out = (float*)d_out;

    unsigned short* xbf = (unsigned short*)((char*)d_ws + OFF_XBF);
    float* rowsumPart   = (float*)((char*)d_ws + OFF_RSP);

    void* args[] = {(void*)&x, (void*)&pi_, (void*)&mu, (void*)&sig,
                    (void*)&xbf, (void*)&rowsumPart, (void*)&out};
    hipError_t err = hipLaunchCooperativeKernel((void*)fused_kernel, dim3(NBLK),
                                                dim3(NTHR), args, 0, stream);
    if (err != hipSuccess) {
        // deterministic fallback: verified R7 pipeline
        rowsum_kernel<<<1024, 256, 0, stream>>>(pi_, mu, sig, rowsumPart);
        dim3 xg(MROWS, BB);
        xbf_kernel<<<xg, 256, 0, stream>>>(x, rowsumPart, xbf);
        dim3 gg(KK / 16, BB);
        gemm_kernel<<<gg, 512, 0, stream>>>(pi_, mu, sig, xbf, out);
    }
}

// Round 10
// 100.897 us; speedup vs baseline: 1.9761x; 1.9761x over previous
//
#include <hip/hip_runtime.h>

// MixtureRouting: y[b,d,m] = sum_p x[b,d,p] * coef[b,p,m]
//   lh[b,p,m]  = pi[b,m] * prod_i( sig[b,i,m] / (PI*((mu[b,i,p]-mu[b,i,m])^2 + sig[b,i,m]^2)) )
//   coef[p,m]  = lh[p,m] / rowsum[p]
// R9 -> R10: cooperative fusion falsified the dispatch-overhead theory (fused ran at
// 126us, VALUBusy 10.5% -> pipeline is latency-bound, not overhead-bound). Revert to
// the verified R7 3-kernel path; raise duty factor:
//   gemm:   __launch_bounds__(512,2) guarantees 2 blocks/CU (16 waves/CU) + explicit
//           A-fragment prefetch pipeline (global loads overlap the lh-eval VALU chain)
//   rowsum: __launch_bounds__(256,4) -> 4 blocks/CU
//   xbf:    unchanged (streaming)

typedef float v4f __attribute__((ext_vector_type(4)));
typedef float f32x4 __attribute__((ext_vector_type(4)));
typedef short bf16x8 __attribute__((ext_vector_type(8)));

namespace {
constexpr int BB = 4;
constexpr int DD = 81;
constexpr int KK = 2048;
constexpr int MROWS = 96;                 // padded d-rows for MFMA (6 tiles of 16)
constexpr float INV_PI4 = 1.0f / 97.40909103400243f;

// ws layout (bytes)
constexpr size_t OFF_XBF = 0;                                     // ushort[B][96][K]
constexpr size_t OFF_RSP = (size_t)BB * MROWS * KK * 2;           // float[B][8][K]
}

__device__ __forceinline__ unsigned short f2bf(float f) {
    union { float f; unsigned int u; } v; v.f = f;
    unsigned int u = v.u;
    unsigned int r = (u + 0x7FFFu + ((u >> 16) & 1u)) >> 16;   // RNE
    return (unsigned short)r;
}

// ---------------------------------------------------------------------------
// rowsum: grid = B * 32 p-chunks * 8 m-slices = 1024 blocks, 256 threads.
// Block (b, p0 = 64-chunk, ms = 256-m slice):
//   rowsumPart[b][ms][p0+lane] = sum over its 256 m of lh[p,m]  (slice-disjoint)
// ---------------------------------------------------------------------------
__global__ __launch_bounds__(256, 4) void rowsum_kernel(const float* __restrict__ pi_,
                                                        const float* __restrict__ mu,
                                                        const float* __restrict__ sig,
                                                        float* __restrict__ rowsumPart) {
    __shared__ v4f   mush[256];
    __shared__ v4f   s2sh[256];
    __shared__ float csh[256];
    __shared__ float red[4][64];

    int blk = blockIdx.x;
    int b   = blk >> 8;
    int pc  = (blk & 255) >> 3;
    int ms  = blk & 7;
    int p0  = pc * 64;
    int m0  = ms * 256;
    int t   = threadIdx.x;
    int lane = t & 63, w = t >> 6;

    const float* mub = mu  + (size_t)b * 4 * KK;
    const float* sgb = sig + (size_t)b * 4 * KK;
    const float* pib = pi_ + (size_t)b * KK;

    {
        int m = m0 + t;
        v4f mm = {mub[m], mub[KK + m], mub[2 * KK + m], mub[3 * KK + m]};
        v4f sg = {sgb[m], sgb[KK + m], sgb[2 * KK + m], sgb[3 * KK + m]};
        mush[t] = mm;
        s2sh[t] = sg * sg;
        csh[t]  = pib[m] * ((sg.x * sg.y) * (sg.z * sg.w)) * INV_PI4;
    }
    int p = p0 + lane;
    v4f mp = {mub[p], mub[KK + p], mub[2 * KK + p], mub[3 * KK + p]};
    __syncthreads();

    float sum = 0.f;
#pragma unroll 8
    for (int i = 0; i < 64; ++i) {
        int mi = w * 64 + i;
        v4f d = mp - mush[mi];
        v4f q = d * d + s2sh[mi];
        float den = (q.x * q.y) * (q.z * q.w);
        sum += csh[mi] * __builtin_amdgcn_rcpf(den);
    }

    red[w][lane] = sum;
    __syncthreads();
    if (t < 64)
        rowsumPart[((size_t)(b * 8 + ms)) * KK + p0 + t] =
            red[0][t] + red[1][t] + red[2][t] + red[3][t];
}

// ---------------------------------------------------------------------------
// xbf: grid (96, B), 256 threads; xbf[b][d][p] = bf16(x[b][d][p] * invrow[p]); d>=81 -> 0
// ---------------------------------------------------------------------------
__global__ __launch_bounds__(256) void xbf_kernel(const float* __restrict__ x,
                                                  const float* __restrict__ rowsumPart,
                                                  unsigned short* __restrict__ xbf) {
    int d = blockIdx.x;
    int b = blockIdx.y;
    int t = threadIdx.x;
    unsigned short* orow = xbf + ((size_t)(b * MROWS + d)) * KK;
    const float* xrow = x + ((size_t)(b * DD + d)) * KK;
    const float* rsp  = rowsumPart + (size_t)b * 8 * KK;
#pragma unroll
    for (int j = 0; j < 8; ++j) {
        int p = j * 256 + t;
        float rs = 0.f;
#pragma unroll
        for (int s = 0; s < 8; ++s) rs += rsp[(size_t)s * KK + p];
        float v = 0.f;
        if (d < DD) v = xrow[p] * __builtin_amdgcn_rcpf(rs);
        orow[p] = f2bf(v);
    }
}

// ---------------------------------------------------------------------------
// gemm (fused lh): grid (128, B), 512 threads = 8 waves; __launch_bounds__(512,2)
// caps VGPR at 128 so 2 blocks/CU co-reside (16 waves/CU). Block = (b, 16-col
// m-tile), full K=2048; wave w owns p-slice [w*256, w*256+256).
// Pipeline: A-frags for step ks+1 are prefetched from global while the lane
// computes its 8-value B-fragment lh[pb..pb+7][m0+r] from LDS-staged mu.
// A[m=lane&15][k=quad*8+j]; B[n=lane&15][k=quad*8+j]; D col=lane&15,row=quad*4+reg.
// Epilogue: cross-wave LDS reduce (reuses mu buffer) + plain coalesced stores.
// ---------------------------------------------------------------------------
__global__ __launch_bounds__(512, 2) void gemm_kernel(const float* __restrict__ pi_,
                                                      const float* __restrict__ mu,
                                                      const float* __restrict__ sig,
                                                      const unsigned short* __restrict__ xbf,
                                                      float* __restrict__ out) {
    __shared__ __align__(16) char smem2[49152];
    v4f* mus = (v4f*)smem2;                             // [2048] 32 KB during K-loop
    f32x4 (*red)[6][64] = (f32x4 (*)[6][64])smem2;      // [8][6][64] 48 KB after barrier

    int t = threadIdx.x;
    int w = t >> 6, lane = t & 63;
    int r = lane & 15, q = lane >> 4;
    int b  = blockIdx.y;
    int m0 = blockIdx.x * 16;

    const float* mub = mu  + (size_t)b * 4 * KK;
    const float* sgb = sig + (size_t)b * 4 * KK;

    for (int i = t; i < KK; i += 512)
        mus[i] = (v4f){mub[i], mub[KK + i], mub[2 * KK + i], mub[3 * KK + i]};

    int m = m0 + r;
    v4f mm = {mub[m], mub[KK + m], mub[2 * KK + m], mub[3 * KK + m]};
    v4f sg = {sgb[m], sgb[KK + m], sgb[2 * KK + m], sgb[3 * KK + m]};
    v4f s2 = sg * sg;
    float cm = pi_[(size_t)b * KK + m] * ((sg.x * sg.y) * (sg.z * sg.w)) * INV_PI4;

    const unsigned short* Abase = xbf + ((size_t)(b * MROWS + r)) * KK;

    f32x4 acc[6];
#pragma unroll
    for (int i = 0; i < 6; ++i) acc[i] = (f32x4)0.f;

    __syncthreads();

    int pw = w * 256;

    // prefetch ks=0 A-fragments
    bf16x8 Af[6];
#pragma unroll
    for (int Mt = 0; Mt < 6; ++Mt)
        Af[Mt] = *(const bf16x8*)(Abase + (size_t)Mt * 16 * KK + pw + q * 8);

#pragma unroll
    for (int ks = 0; ks < 8; ++ks) {
        int pb = pw + ks * 32 + q * 8;

        // start next step's A-loads (overlaps the Bf eval chain below)
        bf16x8 Afn[6];
        if (ks < 7) {
            int pbn = pb + 32;
#pragma unroll
            for (int Mt = 0; Mt < 6; ++Mt)
                Afn[Mt] = *(const bf16x8*)(Abase + (size_t)Mt * 16 * KK + pbn);
        }

        // build B fragment in registers: Bf[j] = bf16(lh[pb+j][m0+r])
        bf16x8 Bf;
#pragma unroll
        for (int j = 0; j < 8; ++j) {
            v4f mp = mus[pb + j];
            v4f dd = mp - mm;
            v4f qq = dd * dd + s2;
            float den = (qq.x * qq.y) * (qq.z * qq.w);
            float lh = cm * __builtin_amdgcn_rcpf(den);
            Bf[j] = (short)f2bf(lh);
        }

#pragma unroll
        for (int Mt = 0; Mt < 6; ++Mt)
            acc[Mt] = __builtin_amdgcn_mfma_f32_16x16x32_bf16(Af[Mt], Bf, acc[Mt], 0, 0, 0);

        if (ks < 7) {
#pragma unroll
            for (int Mt = 0; Mt < 6; ++Mt)
                Af[Mt] = Afn[Mt];
        }
    }

    __syncthreads();                                    // done reading mus
#pragma unroll
    for (int Mt = 0; Mt < 6; ++Mt)
        red[w][Mt][lane] = acc[Mt];
    __syncthreads();

    // 1536 outputs (96 rows x 16 cols) -> 3 per thread; skip d >= 81.
    int col = t & 15;
    int dr  = t >> 4;                                   // 0..31
#pragma unroll
    for (int k = 0; k < 3; ++k) {
        int d = dr + 32 * k;                            // 0..95
        if (d < DD) {
            int Mt  = d >> 4;
            int row = d & 15;
            int l   = (row >> 2) * 16 + col;
            int j   = row & 3;
            float s = 0.f;
#pragma unroll
            for (int ww = 0; ww < 8; ++ww) s += red[ww][Mt][l][j];
            out[((size_t)(b * DD + d)) * KK + m0 + col] = s;
        }
    }
}

extern "C" void kernel_launch(void* const* d_in, const int* in_sizes, int n_in,
                              void* d_out, int out_size, void* d_ws, size_t ws_size,
                              hipStream_t stream) {
    const float* x   = (const float*)d_in[0];
    const float* pi_ = (const float*)d_in[1];
    const float* mu  = (const float*)d_in[2];
    const float* sig = (const float*)d_in[3];
    float* out = (float*)d_out;

    unsigned short* xbf = (unsigned short*)((char*)d_ws + OFF_XBF);
    float* rowsumPart   = (float*)((char*)d_ws + OFF_RSP);

    rowsum_kernel<<<1024, 256, 0, stream>>>(pi_, mu, sig, rowsumPart);
    dim3 xg(MROWS, BB);
    xbf_kernel<<<xg, 256, 0, stream>>>(x, rowsumPart, xbf);
    dim3 gg(KK / 16, BB);
    gemm_kernel<<<gg, 512, 0, stream>>>(pi_, mu, sig, xbf, out);
}